// Round 6
// baseline (247.516 us; speedup 1.0000x reference)
//
#include <hip/hip_runtime.h>
#include <hip/hip_bf16.h>

#define NTOK 19950
#define NTOK2 9975
#define KTOP 300
#define NB 8
#define NQ (NB * KTOP)   // 2400
#define QDIM 520         // 515 padded to 520

typedef float f32x4 __attribute__((ext_vector_type(4)));

__device__ __forceinline__ uint32_t fkey(float f) {
    uint32_t u = __float_as_uint(f);
    return (u & 0x80000000u) ? ~u : (u | 0x80000000u);
}

// ---------------- K1: objectness scores (float2, 8B/lane) ----------------
__global__ __launch_bounds__(256) void score_kernel(
    const float* __restrict__ f0, const float* __restrict__ f1, const float* __restrict__ f2,
    const float* __restrict__ conv_w, const float* __restrict__ conv_b,
    float* __restrict__ scores)
{
    __shared__ float cw[256];
    cw[threadIdx.x] = conv_w[threadIdx.x];
    __syncthreads();
    int t = blockIdx.x * 256 + threadIdx.x;
    if (t >= NB * NTOK2) return;
    int b = t / NTOK2;
    int pos = (t - b * NTOK2) * 2;
    const float* f; int HWl, hw;
    if (pos < 15200)      { f = f0; HWl = 15200; hw = pos; }
    else if (pos < 19000) { f = f1; HWl = 3800;  hw = pos - 15200; }
    else                  { f = f2; HWl = 950;   hw = pos - 19000; }
    const float2* base = (const float2*)(f + (size_t)b * 256 * HWl + hw);
    const int stride2 = HWl >> 1;
    float s0 = 0.0f, s1 = 0.0f;
    #pragma unroll 16
    for (int c = 0; c < 256; ++c) {
        float2 v = base[(size_t)c * stride2];
        s0 += v.x * cw[c];
        s1 += v.y * cw[c];
    }
    scores[b * NTOK + pos]     = s0 + conv_b[0];
    scores[b * NTOK + pos + 1] = s1 + conv_b[0];
}

// ---------------- K2: exact top-K (radix select) + query gather -> Q ----------------
__global__ __launch_bounds__(1024, 1) void topk_gather_kernel(
    const float* __restrict__ scores,
    const float* __restrict__ f0, const float* __restrict__ f1, const float* __restrict__ f2,
    const float* __restrict__ level_emb, float* __restrict__ Q)
{
    __shared__ uint32_t key[NTOK];           // 79.8 KB
    __shared__ int whist[16][256];           // 16 KB
    __shared__ int suffix[256];              // 1 KB
    __shared__ uint32_t s_prefix;
    __shared__ int s_Kr, s_cnt, s_tcnt;
    __shared__ int tie[1024];                // 4 KB
    __shared__ int sel[KTOP];                // selected token indices
    __shared__ int g_lvl[KTOP], g_hw[KTOP], g_HW[KTOP];
    const int tid = threadIdx.x;
    const int wv = tid >> 6;                 // wave id 0..15
    const int b = blockIdx.x;
    const float* srow = scores + b * NTOK;
    for (int i = tid; i < NTOK; i += 1024) key[i] = fkey(srow[i]);
    if (tid == 0) { s_prefix = 0u; s_Kr = KTOP; }
    __syncthreads();
    uint32_t pmask = 0u;
    for (int pass = 0; pass < 4; ++pass) {
        const int shift = 24 - 8 * pass;
        for (int i = tid; i < 16 * 256; i += 1024) ((int*)whist)[i] = 0;
        __syncthreads();
        const uint32_t prefix = s_prefix;
        const int Kr = s_Kr;
        for (int i = tid; i < NTOK; i += 1024) {
            uint32_t k = key[i];
            if ((k & pmask) == prefix) atomicAdd(&whist[wv][(k >> shift) & 255], 1);
        }
        __syncthreads();
        if (tid < 256) {
            int s = 0;
            #pragma unroll
            for (int w = 0; w < 16; ++w) s += whist[w][tid];
            suffix[tid] = s;
        }
        __syncthreads();
        for (int off = 1; off < 256; off <<= 1) {
            int t = 0;
            if (tid < 256 && tid + off < 256) t = suffix[tid + off];
            __syncthreads();
            if (tid < 256) suffix[tid] += t;
            __syncthreads();
        }
        if (tid < 256) {
            int sgeq = suffix[tid];
            int sgt  = (tid < 255) ? suffix[tid + 1] : 0;
            if (sgeq >= Kr && sgt < Kr) {
                s_prefix = prefix | ((uint32_t)tid << shift);
                s_Kr = Kr - sgt;
            }
        }
        __syncthreads();
        pmask |= (0xFFu << shift);
    }
    const uint32_t T = s_prefix;
    const int need = s_Kr;                   // #ties (key == T) to include
    if (tid == 0) { s_cnt = 0; s_tcnt = 0; }
    __syncthreads();
    for (int i = tid; i < NTOK; i += 1024) {
        uint32_t k = key[i];
        if (k > T) {
            int p = atomicAdd(&s_cnt, 1);
            sel[p] = i;
        } else if (k == T) {
            int p = atomicAdd(&s_tcnt, 1);
            if (p < 1024) tie[p] = i;
        }
    }
    __syncthreads();
    if (tid == 0) {
        int base = s_cnt;
        int tcnt = s_tcnt > 1024 ? 1024 : s_tcnt;
        for (int s = 0; s < need; ++s) {     // pick 'need' smallest tie indices
            int mi = s;
            for (int u = s + 1; u < tcnt; ++u) if (tie[u] < tie[mi]) mi = u;
            int tmp = tie[s]; tie[s] = tie[mi]; tie[mi] = tmp;
            sel[base + s] = tie[s];
        }
    }
    __syncthreads();
    // ---- per-query meta + tail of Q row
    if (tid < KTOP) {
        const int idx = sel[tid];
        int lvl, hw, HWl, Wl, Hl;
        if (idx < 15200)      { lvl = 0; hw = idx;         HWl = 15200; Wl = 152; Hl = 100; }
        else if (idx < 19000) { lvl = 1; hw = idx - 15200; HWl = 3800;  Wl = 76;  Hl = 50;  }
        else                  { lvl = 2; hw = idx - 19000; HWl = 950;   Wl = 38;  Hl = 25;  }
        g_lvl[tid] = lvl; g_hw[tid] = hw; g_HW[tid] = HWl;
        int hh = hw / Wl, ww = hw - hh * Wl;
        float x = -1.0f + 2.0f * (float)ww / (float)(Wl - 1);
        float y = -1.0f + 2.0f * (float)hh / (float)(Hl - 1);
        float sv = srow[idx];
        float sp = 1.0f / (1.0f + expf(-sv));
        float* qr = Q + (size_t)(b * KTOP + tid) * QDIM;
        qr[512] = x; qr[513] = y; qr[514] = sp;
        qr[515] = 0.0f; qr[516] = 0.0f; qr[517] = 0.0f; qr[518] = 0.0f; qr[519] = 0.0f;
    }
    __syncthreads();
    // ---- channel gather: 300 queries x 256 channels (f is L3-resident after K1)
    for (int j = tid; j < KTOP * 256; j += 1024) {
        const int k = j >> 8, c = j & 255;
        const int lvl = g_lvl[k];
        const float* f = (lvl == 0) ? f0 : ((lvl == 1) ? f1 : f2);
        float* qr = Q + (size_t)(b * KTOP + k) * QDIM;
        qr[c]       = f[((size_t)b * 256 + c) * g_HW[k] + g_hw[k]];
        qr[256 + c] = level_emb[lvl * 256 + c];
    }
}

// ---------------- K3: MLP (Q -> per-query gates G[2400][3]) ----------------
#define QT 8
__global__ __launch_bounds__(512, 1) void mlp_kernel(
    const float* __restrict__ Q,
    const float* __restrict__ w1, const float* __restrict__ b1,
    const float* __restrict__ w2, const float* __restrict__ b2,
    const float* __restrict__ gate_w, const float* __restrict__ gate_b,
    float* __restrict__ G)
{
    __shared__ __align__(16) float q[QT][QDIM];     // 16.6 KB (queries; later holds h2)
    __shared__ __align__(16) float part[QT][256];   // 8 KB
    __shared__ __align__(16) float h[QT][256];      // 8 KB
    const int tid = threadIdx.x;
    const int out = tid & 255;
    const int kh = tid >> 8;                        // K-half: 0 or 1
    const int k0 = blockIdx.x * QT;                 // 300 blocks, all full

    {
        const float4* Qg = (const float4*)(Q + (size_t)k0 * QDIM);
        float4* qs = (float4*)&q[0][0];
        for (int i = tid; i < QT * QDIM / 4; i += 512) qs[i] = Qg[i];
    }
    __syncthreads();

    float acc[QT];

    // ---- layer 1
    {
        #pragma unroll
        for (int t = 0; t < QT; ++t) acc[t] = 0.0f;
        const float* wp = w1 + (size_t)(kh * 256) * 256 + out;
        float a0 = wp[0], a1 = wp[256], a2 = wp[512], a3 = wp[768];
        for (int i4 = 0; i4 < 64; ++i4) {
            float c0 = a0, c1 = a1, c2 = a2, c3 = a3;
            const float* wn = wp + 1024;
            if (i4 < 63) { a0 = wn[0]; a1 = wn[256]; a2 = wn[512]; a3 = wn[768]; }
            wp = wn;
            const int kb = kh * 256 + i4 * 4;
            #pragma unroll
            for (int t = 0; t < QT; ++t) {
                float4 qv = *reinterpret_cast<const float4*>(&q[t][kb]);
                acc[t] += qv.x * c0 + qv.y * c1 + qv.z * c2 + qv.w * c3;
            }
        }
        if (kh) {
            for (int r = 512; r < 515; ++r) {
                float wv = w1[(size_t)r * 256 + out];
                #pragma unroll
                for (int t = 0; t < QT; ++t) acc[t] += q[t][r] * wv;
            }
            #pragma unroll
            for (int t = 0; t < QT; ++t) part[t][out] = acc[t];
        }
    }
    __syncthreads();
    if (kh == 0) {
        float bj = b1[out];
        #pragma unroll
        for (int t = 0; t < QT; ++t) h[t][out] = fmaxf(acc[t] + part[t][out] + bj, 0.0f);
    }
    __syncthreads();

    // ---- layer 2
    {
        #pragma unroll
        for (int t = 0; t < QT; ++t) acc[t] = 0.0f;
        const float* wp = w2 + (size_t)(kh * 128) * 256 + out;
        float a0 = wp[0], a1 = wp[256], a2 = wp[512], a3 = wp[768];
        for (int i4 = 0; i4 < 32; ++i4) {
            float c0 = a0, c1 = a1, c2 = a2, c3 = a3;
            const float* wn = wp + 1024;
            if (i4 < 31) { a0 = wn[0]; a1 = wn[256]; a2 = wn[512]; a3 = wn[768]; }
            wp = wn;
            const int kb = kh * 128 + i4 * 4;
            #pragma unroll
            for (int t = 0; t < QT; ++t) {
                float4 hv = *reinterpret_cast<const float4*>(&h[t][kb]);
                acc[t] += hv.x * c0 + hv.y * c1 + hv.z * c2 + hv.w * c3;
            }
        }
        if (kh) {
            #pragma unroll
            for (int t = 0; t < QT; ++t) part[t][out] = acc[t];
        }
    }
    __syncthreads();
    if (kh == 0) {
        float bj = b2[out];
        #pragma unroll
        for (int t = 0; t < QT; ++t) q[t][out] = fmaxf(acc[t] + part[t][out] + bj, 0.0f);
    }
    __syncthreads();

    // ---- gate
    if (tid < 256) {
        const int t = tid >> 5, seg = tid & 31;
        float l0 = 0.f, l1 = 0.f, l2 = 0.f;
        for (int c = seg * 8; c < seg * 8 + 8; ++c) {
            float hv = q[t][c];
            l0 += hv * gate_w[c * 8 + 0];
            l1 += hv * gate_w[c * 8 + 1];
            l2 += hv * gate_w[c * 8 + 2];
        }
        float* gp = &part[0][0];
        gp[(t * 32 + seg) * 3 + 0] = l0;
        gp[(t * 32 + seg) * 3 + 1] = l1;
        gp[(t * 32 + seg) * 3 + 2] = l2;
    }
    __syncthreads();
    if (tid < QT) {
        const int t = tid;
        float l0 = gate_b[0], l1 = gate_b[1], l2 = gate_b[2];
        const float* gp = &part[0][0];
        for (int seg = 0; seg < 32; ++seg) {
            l0 += gp[(t * 32 + seg) * 3 + 0];
            l1 += gp[(t * 32 + seg) * 3 + 1];
            l2 += gp[(t * 32 + seg) * 3 + 2];
        }
        float m = fmaxf(l0, fmaxf(l1, l2));
        float e0 = expf(l0 - m), e1 = expf(l1 - m), e2 = expf(l2 - m);
        float inv = 1.0f / (e0 + e1 + e2);
        G[(k0 + t) * 3 + 0] = e0 * inv;
        G[(k0 + t) * 3 + 1] = e1 * inv;
        G[(k0 + t) * 3 + 2] = e2 * inv;
    }
}

// ---------------- K4: scale reduce (per block, deterministic) + streaming multiply ----
__global__ __launch_bounds__(256) void out_kernel(
    const f32x4* __restrict__ f0, const f32x4* __restrict__ f1, const f32x4* __restrict__ f2,
    const float* __restrict__ G, const float* __restrict__ rs, f32x4* __restrict__ out)
{
    __shared__ float red[3][32];
    __shared__ float ssc[3];
    const int b = blockIdx.y;
    const int tid = threadIdx.x;
    // fixed-order chunked sum of G[b*300 .. +300][l] (deterministic)
    if (tid < 96) {
        const int l = tid / 32, c = tid % 32;
        float s = 0.0f;
        const int kb = c * 10;
        const int ke = (kb + 10 < KTOP) ? kb + 10 : KTOP;
        for (int k = kb; k < ke; ++k) s += G[(size_t)(b * KTOP + k) * 3 + l];
        red[l][c] = s;
    }
    __syncthreads();
    for (int off = 16; off > 0; off >>= 1) {
        if (tid < 96) {
            const int l = tid / 32, c = tid % 32;
            if (c < off) red[l][c] += red[l][c + off];
        }
        __syncthreads();
    }
    if (tid < 3) ssc[tid] = 1.0f + rs[0] * (red[tid][0] / (float)KTOP);
    __syncthreads();

    const int t0 = blockIdx.x * 256 + tid;
    const int TPB = gridDim.x * 256;
    f32x4* ob = out + (size_t)b * 1276800;
    {
        const float sc = ssc[0];
        const f32x4* src = f0 + (size_t)b * 972800;
        for (int r = t0; r < 972800; r += TPB)
            __builtin_nontemporal_store(src[r] * sc, &ob[r]);
    }
    {
        const float sc = ssc[1];
        const f32x4* src = f1 + (size_t)b * 243200;
        f32x4* o1 = ob + 972800;
        for (int r = t0; r < 243200; r += TPB)
            __builtin_nontemporal_store(src[r] * sc, &o1[r]);
    }
    {
        const float sc = ssc[2];
        const f32x4* src = f2 + (size_t)b * 60800;
        f32x4* o2 = ob + 1216000;
        for (int r = t0; r < 60800; r += TPB)
            __builtin_nontemporal_store(src[r] * sc, &o2[r]);
    }
}

extern "C" void kernel_launch(void* const* d_in, const int* in_sizes, int n_in,
                              void* d_out, int out_size, void* d_ws, size_t ws_size,
                              hipStream_t stream)
{
    const float* f0        = (const float*)d_in[0];
    const float* f1        = (const float*)d_in[1];
    const float* f2        = (const float*)d_in[2];
    const float* conv_w    = (const float*)d_in[3];
    const float* conv_b    = (const float*)d_in[4];
    const float* level_emb = (const float*)d_in[5];
    const float* w1        = (const float*)d_in[6];
    const float* b1        = (const float*)d_in[7];
    const float* w2        = (const float*)d_in[8];
    const float* b2        = (const float*)d_in[9];
    const float* gate_w    = (const float*)d_in[10];
    const float* gate_b    = (const float*)d_in[11];
    const float* rs        = (const float*)d_in[12];

    char* ws = (char*)d_ws;
    float* scores   = (float*)ws;                   // 638.4 KB
    float* G        = (float*)(ws + 656 * 1024);    // 28.8 KB
    float* Q        = (float*)(ws + 704 * 1024);    // 2400*520*4 = 4.99 MB

    score_kernel<<<(NB * NTOK2 + 255) / 256, 256, 0, stream>>>(
        f0, f1, f2, conv_w, conv_b, scores);
    topk_gather_kernel<<<NB, 1024, 0, stream>>>(scores, f0, f1, f2, level_emb, Q);
    mlp_kernel<<<NQ / QT, 512, 0, stream>>>(Q, w1, b1, w2, b2, gate_w, gate_b, G);
    out_kernel<<<dim3(256, NB), 256, 0, stream>>>((const f32x4*)f0, (const f32x4*)f1,
                                                  (const f32x4*)f2, G, rs, (f32x4*)d_out);
}

// Round 7
// 159.340 us; speedup vs baseline: 1.5534x; 1.5534x over previous
//
#include <hip/hip_runtime.h>
#include <hip/hip_bf16.h>

#define NTOK 19950
#define NTOK2 9975
#define KTOP 300
#define NB 8
#define NQ (NB * KTOP)   // 2400
#define QDIM 520         // 515 padded to 520

typedef float f32x4 __attribute__((ext_vector_type(4)));

__device__ __forceinline__ uint32_t fkey(float f) {
    uint32_t u = __float_as_uint(f);
    return (u & 0x80000000u) ? ~u : (u | 0x80000000u);
}

// ---------------- K1: objectness scores (float2, 8B/lane) ----------------
__global__ __launch_bounds__(256) void score_kernel(
    const float* __restrict__ f0, const float* __restrict__ f1, const float* __restrict__ f2,
    const float* __restrict__ conv_w, const float* __restrict__ conv_b,
    float* __restrict__ scores)
{
    __shared__ float cw[256];
    cw[threadIdx.x] = conv_w[threadIdx.x];
    __syncthreads();
    int t = blockIdx.x * 256 + threadIdx.x;
    if (t >= NB * NTOK2) return;
    int b = t / NTOK2;
    int pos = (t - b * NTOK2) * 2;
    const float* f; int HWl, hw;
    if (pos < 15200)      { f = f0; HWl = 15200; hw = pos; }
    else if (pos < 19000) { f = f1; HWl = 3800;  hw = pos - 15200; }
    else                  { f = f2; HWl = 950;   hw = pos - 19000; }
    const float2* base = (const float2*)(f + (size_t)b * 256 * HWl + hw);
    const int stride2 = HWl >> 1;
    float s0 = 0.0f, s1 = 0.0f;
    #pragma unroll 16
    for (int c = 0; c < 256; ++c) {
        float2 v = base[(size_t)c * stride2];
        s0 += v.x * cw[c];
        s1 += v.y * cw[c];
    }
    scores[b * NTOK + pos]     = s0 + conv_b[0];
    scores[b * NTOK + pos + 1] = s1 + conv_b[0];
}

// ---------------- K2: exact top-K via radix select (per batch) ----------------
__global__ __launch_bounds__(1024, 1) void topk_kernel(
    const float* __restrict__ scores, int* __restrict__ top_idx)
{
    __shared__ uint32_t key[NTOK];           // 79.8 KB
    __shared__ int whist[16][256];           // 16 KB
    __shared__ int suffix[256];              // 1 KB
    __shared__ uint32_t s_prefix;
    __shared__ int s_Kr, s_cnt, s_tcnt;
    __shared__ int tie[1024];                // 4 KB
    const int tid = threadIdx.x;
    const int wv = tid >> 6;                 // wave id 0..15
    const int b = blockIdx.x;
    const float* srow = scores + b * NTOK;
    for (int i = tid; i < NTOK; i += 1024) key[i] = fkey(srow[i]);
    if (tid == 0) { s_prefix = 0u; s_Kr = KTOP; }
    __syncthreads();
    uint32_t pmask = 0u;
    for (int pass = 0; pass < 4; ++pass) {
        const int shift = 24 - 8 * pass;
        for (int i = tid; i < 16 * 256; i += 1024) ((int*)whist)[i] = 0;
        __syncthreads();
        const uint32_t prefix = s_prefix;
        const int Kr = s_Kr;
        for (int i = tid; i < NTOK; i += 1024) {
            uint32_t k = key[i];
            if ((k & pmask) == prefix) atomicAdd(&whist[wv][(k >> shift) & 255], 1);
        }
        __syncthreads();
        if (tid < 256) {
            int s = 0;
            #pragma unroll
            for (int w = 0; w < 16; ++w) s += whist[w][tid];
            suffix[tid] = s;
        }
        __syncthreads();
        for (int off = 1; off < 256; off <<= 1) {
            int t = 0;
            if (tid < 256 && tid + off < 256) t = suffix[tid + off];
            __syncthreads();
            if (tid < 256) suffix[tid] += t;
            __syncthreads();
        }
        if (tid < 256) {
            int sgeq = suffix[tid];
            int sgt  = (tid < 255) ? suffix[tid + 1] : 0;
            if (sgeq >= Kr && sgt < Kr) {
                s_prefix = prefix | ((uint32_t)tid << shift);
                s_Kr = Kr - sgt;
            }
        }
        __syncthreads();
        pmask |= (0xFFu << shift);
    }
    const uint32_t T = s_prefix;
    const int need = s_Kr;                   // #ties (key == T) to include
    if (tid == 0) { s_cnt = 0; s_tcnt = 0; }
    __syncthreads();
    for (int i = tid; i < NTOK; i += 1024) {
        uint32_t k = key[i];
        if (k > T) {
            int p = atomicAdd(&s_cnt, 1);
            top_idx[b * KTOP + p] = i;
        } else if (k == T) {
            int p = atomicAdd(&s_tcnt, 1);
            if (p < 1024) tie[p] = i;
        }
    }
    __syncthreads();
    if (tid == 0) {
        int base = s_cnt;
        int tcnt = s_tcnt > 1024 ? 1024 : s_tcnt;
        for (int s = 0; s < need; ++s) {     // pick 'need' smallest tie indices
            int mi = s;
            for (int u = s + 1; u < tcnt; ++u) if (tie[u] < tie[mi]) mi = u;
            int tmp = tie[s]; tie[s] = tie[mi]; tie[mi] = tmp;
            top_idx[b * KTOP + base + s] = tie[s];
        }
    }
}

// ---------------- K2.5: gather queries -> Q[2400][520] (one block per query) ----------------
__global__ __launch_bounds__(256) void gather_kernel(
    const float* __restrict__ f0, const float* __restrict__ f1, const float* __restrict__ f2,
    const float* __restrict__ scores, const int* __restrict__ top_idx,
    const float* __restrict__ level_emb, float* __restrict__ Q)
{
    const int k = blockIdx.x;            // 0..2399
    const int b = k / KTOP;
    const int idx = top_idx[k];
    int lvl, hw, HWl, Wl, Hl;
    if (idx < 15200)      { lvl = 0; hw = idx;         HWl = 15200; Wl = 152; Hl = 100; }
    else if (idx < 19000) { lvl = 1; hw = idx - 15200; HWl = 3800;  Wl = 76;  Hl = 50;  }
    else                  { lvl = 2; hw = idx - 19000; HWl = 950;   Wl = 38;  Hl = 25;  }
    const float* f = (lvl == 0) ? f0 : ((lvl == 1) ? f1 : f2);
    const int c = threadIdx.x;
    float* qr = Q + (size_t)k * QDIM;
    qr[c]       = f[((size_t)b * 256 + c) * HWl + hw];
    qr[256 + c] = level_emb[lvl * 256 + c];
    if (c < 8) {
        float v = 0.0f;
        if (c == 0) {
            int hh = hw / Wl, ww = hw - hh * Wl;
            v = -1.0f + 2.0f * (float)ww / (float)(Wl - 1);
        } else if (c == 1) {
            int hh = hw / Wl;
            v = -1.0f + 2.0f * (float)hh / (float)(Hl - 1);
        } else if (c == 2) {
            float sv = scores[b * NTOK + idx];
            v = 1.0f / (1.0f + expf(-sv));
        }
        qr[512 + c] = v;
    }
}

// ---------------- K3: MLP (Q -> per-query gates G[2400][3]) ----------------
#define QT 8
__global__ __launch_bounds__(512, 1) void mlp_kernel(
    const float* __restrict__ Q,
    const float* __restrict__ w1, const float* __restrict__ b1,
    const float* __restrict__ w2, const float* __restrict__ b2,
    const float* __restrict__ gate_w, const float* __restrict__ gate_b,
    float* __restrict__ G)
{
    __shared__ __align__(16) float q[QT][QDIM];     // 16.6 KB (queries; later holds h2)
    __shared__ __align__(16) float part[QT][256];   // 8 KB
    __shared__ __align__(16) float h[QT][256];      // 8 KB
    const int tid = threadIdx.x;
    const int out = tid & 255;
    const int kh = tid >> 8;                        // K-half: 0 or 1
    const int k0 = blockIdx.x * QT;                 // 300 blocks, all full

    {
        const float4* Qg = (const float4*)(Q + (size_t)k0 * QDIM);
        float4* qs = (float4*)&q[0][0];
        for (int i = tid; i < QT * QDIM / 4; i += 512) qs[i] = Qg[i];
    }
    __syncthreads();

    float acc[QT];

    // ---- layer 1
    {
        #pragma unroll
        for (int t = 0; t < QT; ++t) acc[t] = 0.0f;
        const float* wp = w1 + (size_t)(kh * 256) * 256 + out;
        float a0 = wp[0], a1 = wp[256], a2 = wp[512], a3 = wp[768];
        for (int i4 = 0; i4 < 64; ++i4) {
            float c0 = a0, c1 = a1, c2 = a2, c3 = a3;
            const float* wn = wp + 1024;
            if (i4 < 63) { a0 = wn[0]; a1 = wn[256]; a2 = wn[512]; a3 = wn[768]; }
            wp = wn;
            const int kb = kh * 256 + i4 * 4;
            #pragma unroll
            for (int t = 0; t < QT; ++t) {
                float4 qv = *reinterpret_cast<const float4*>(&q[t][kb]);
                acc[t] += qv.x * c0 + qv.y * c1 + qv.z * c2 + qv.w * c3;
            }
        }
        if (kh) {
            for (int r = 512; r < 515; ++r) {
                float wv = w1[(size_t)r * 256 + out];
                #pragma unroll
                for (int t = 0; t < QT; ++t) acc[t] += q[t][r] * wv;
            }
            #pragma unroll
            for (int t = 0; t < QT; ++t) part[t][out] = acc[t];
        }
    }
    __syncthreads();
    if (kh == 0) {
        float bj = b1[out];
        #pragma unroll
        for (int t = 0; t < QT; ++t) h[t][out] = fmaxf(acc[t] + part[t][out] + bj, 0.0f);
    }
    __syncthreads();

    // ---- layer 2
    {
        #pragma unroll
        for (int t = 0; t < QT; ++t) acc[t] = 0.0f;
        const float* wp = w2 + (size_t)(kh * 128) * 256 + out;
        float a0 = wp[0], a1 = wp[256], a2 = wp[512], a3 = wp[768];
        for (int i4 = 0; i4 < 32; ++i4) {
            float c0 = a0, c1 = a1, c2 = a2, c3 = a3;
            const float* wn = wp + 1024;
            if (i4 < 31) { a0 = wn[0]; a1 = wn[256]; a2 = wn[512]; a3 = wn[768]; }
            wp = wn;
            const int kb = kh * 128 + i4 * 4;
            #pragma unroll
            for (int t = 0; t < QT; ++t) {
                float4 hv = *reinterpret_cast<const float4*>(&h[t][kb]);
                acc[t] += hv.x * c0 + hv.y * c1 + hv.z * c2 + hv.w * c3;
            }
        }
        if (kh) {
            #pragma unroll
            for (int t = 0; t < QT; ++t) part[t][out] = acc[t];
        }
    }
    __syncthreads();
    if (kh == 0) {
        float bj = b2[out];
        #pragma unroll
        for (int t = 0; t < QT; ++t) q[t][out] = fmaxf(acc[t] + part[t][out] + bj, 0.0f);
    }
    __syncthreads();

    // ---- gate
    if (tid < 256) {
        const int t = tid >> 5, seg = tid & 31;
        float l0 = 0.f, l1 = 0.f, l2 = 0.f;
        for (int c = seg * 8; c < seg * 8 + 8; ++c) {
            float hv = q[t][c];
            l0 += hv * gate_w[c * 8 + 0];
            l1 += hv * gate_w[c * 8 + 1];
            l2 += hv * gate_w[c * 8 + 2];
        }
        float* gp = &part[0][0];
        gp[(t * 32 + seg) * 3 + 0] = l0;
        gp[(t * 32 + seg) * 3 + 1] = l1;
        gp[(t * 32 + seg) * 3 + 2] = l2;
    }
    __syncthreads();
    if (tid < QT) {
        const int t = tid;
        float l0 = gate_b[0], l1 = gate_b[1], l2 = gate_b[2];
        const float* gp = &part[0][0];
        for (int seg = 0; seg < 32; ++seg) {
            l0 += gp[(t * 32 + seg) * 3 + 0];
            l1 += gp[(t * 32 + seg) * 3 + 1];
            l2 += gp[(t * 32 + seg) * 3 + 2];
        }
        float m = fmaxf(l0, fmaxf(l1, l2));
        float e0 = expf(l0 - m), e1 = expf(l1 - m), e2 = expf(l2 - m);
        float inv = 1.0f / (e0 + e1 + e2);
        G[(k0 + t) * 3 + 0] = e0 * inv;
        G[(k0 + t) * 3 + 1] = e1 * inv;
        G[(k0 + t) * 3 + 2] = e2 * inv;
    }
}

// ---------------- K4: scale reduce (per block, deterministic) + streaming multiply ----
__global__ __launch_bounds__(256) void out_kernel(
    const f32x4* __restrict__ f0, const f32x4* __restrict__ f1, const f32x4* __restrict__ f2,
    const float* __restrict__ G, const float* __restrict__ rs, f32x4* __restrict__ out)
{
    __shared__ float red[3][32];
    __shared__ float ssc[3];
    const int b = blockIdx.y;
    const int tid = threadIdx.x;
    // fixed-order chunked sum of G[b*300 .. +300][l] (deterministic)
    if (tid < 96) {
        const int l = tid / 32, c = tid % 32;
        float s = 0.0f;
        const int kb = c * 10;
        const int ke = (kb + 10 < KTOP) ? kb + 10 : KTOP;
        for (int k = kb; k < ke; ++k) s += G[(size_t)(b * KTOP + k) * 3 + l];
        red[l][c] = s;
    }
    __syncthreads();
    for (int off = 16; off > 0; off >>= 1) {
        if (tid < 96) {
            const int l = tid / 32, c = tid % 32;
            if (c < off) red[l][c] += red[l][c + off];
        }
        __syncthreads();
    }
    if (tid < 3) ssc[tid] = 1.0f + rs[0] * (red[tid][0] / (float)KTOP);
    __syncthreads();

    const int t0 = blockIdx.x * 256 + tid;
    const int TPB = gridDim.x * 256;
    f32x4* ob = out + (size_t)b * 1276800;
    {
        const float sc = ssc[0];
        const f32x4* src = f0 + (size_t)b * 972800;
        for (int r = t0; r < 972800; r += TPB)
            __builtin_nontemporal_store(src[r] * sc, &ob[r]);
    }
    {
        const float sc = ssc[1];
        const f32x4* src = f1 + (size_t)b * 243200;
        f32x4* o1 = ob + 972800;
        for (int r = t0; r < 243200; r += TPB)
            __builtin_nontemporal_store(src[r] * sc, &o1[r]);
    }
    {
        const float sc = ssc[2];
        const f32x4* src = f2 + (size_t)b * 60800;
        f32x4* o2 = ob + 1216000;
        for (int r = t0; r < 60800; r += TPB)
            __builtin_nontemporal_store(src[r] * sc, &o2[r]);
    }
}

extern "C" void kernel_launch(void* const* d_in, const int* in_sizes, int n_in,
                              void* d_out, int out_size, void* d_ws, size_t ws_size,
                              hipStream_t stream)
{
    const float* f0        = (const float*)d_in[0];
    const float* f1        = (const float*)d_in[1];
    const float* f2        = (const float*)d_in[2];
    const float* conv_w    = (const float*)d_in[3];
    const float* conv_b    = (const float*)d_in[4];
    const float* level_emb = (const float*)d_in[5];
    const float* w1        = (const float*)d_in[6];
    const float* b1        = (const float*)d_in[7];
    const float* w2        = (const float*)d_in[8];
    const float* b2        = (const float*)d_in[9];
    const float* gate_w    = (const float*)d_in[10];
    const float* gate_b    = (const float*)d_in[11];
    const float* rs        = (const float*)d_in[12];

    char* ws = (char*)d_ws;
    float* scores   = (float*)ws;                   // 638.4 KB
    int*   top_idx  = (int*)(ws + 640 * 1024);      // 9.6 KB
    float* G        = (float*)(ws + 656 * 1024);    // 28.8 KB
    float* Q        = (float*)(ws + 704 * 1024);    // 2400*520*4 = 4.99 MB

    score_kernel<<<(NB * NTOK2 + 255) / 256, 256, 0, stream>>>(
        f0, f1, f2, conv_w, conv_b, scores);
    topk_kernel<<<NB, 1024, 0, stream>>>(scores, top_idx);
    gather_kernel<<<NQ, 256, 0, stream>>>(f0, f1, f2, scores, top_idx, level_emb, Q);
    mlp_kernel<<<NQ / QT, 512, 0, stream>>>(Q, w1, b1, w2, b2, gate_w, gate_b, G);
    out_kernel<<<dim3(256, NB), 256, 0, stream>>>((const f32x4*)f0, (const f32x4*)f1,
                                                  (const f32x4*)f2, G, rs, (f32x4*)d_out);
}